// Round 1
// baseline (23006.966 us; speedup 1.0000x reference)
//
#include <hip/hip_runtime.h>
#include <hip/hip_bf16.h>

// TGCN: B=64, T=500, N=21, HID=128.
// Strategy: one block per batch element (64 blocks x 896 threads), full T-loop
// in-kernel with H1/H2 in LDS. Algebraic refactor:
//   layer1: gcn(X,W,b) is rank-1 in nodes -> fold W@lw_top into a 128-vector.
//   layer2: (A@(H1@W))@lw_top = (A@H1)@(W@lw_top): fuse weights, share AH1.
// Weights repacked into [k/4][col] float4 chunks in d_ws for coalesced loads.
// All precompute in fp64 (closer to the fp64 numpy ref), main loop fp32 FMA,
// output accumulation in fp64.

#define NN 21
#define HID 128
#define TSTEPS 500
#define EDGES 210

// ws layout (float offsets)
#define WS_A     0        // 441 floats (pad to 448)
#define WS_VEC   448      // 9*128: [we_z1, we_r1, we_h1, c_z1, c_r1, c_h1, c_z2, c_r2, c_h2]
#define WS_LZR1  1600     // 32*256*4
#define WS_LH1   34368    // 32*128*4
#define WS_WE2   50752    // 32*384*4
#define WS_LZR2  99904    // 32*256*4
#define WS_LH2   132672   // 32*128*4
#define WS_TOTAL 149056   // ~596 KB

__device__ __forceinline__ float fma4(float4 a, float4 b, float acc) {
    acc = fmaf(a.x, b.x, acc);
    acc = fmaf(a.y, b.y, acc);
    acc = fmaf(a.z, b.z, acc);
    acc = fmaf(a.w, b.w, acc);
    return acc;
}

__device__ __forceinline__ float sigmoidf(float v) {
    return 1.0f / (1.0f + expf(-v));
}

// ---- Prologue: build normalized adjacency A (21x21) in fp64, store fp32 ----
__global__ void build_A(const int* __restrict__ ei, const float* __restrict__ ew,
                        float* __restrict__ Aout) {
    __shared__ double deg[NN];
    __shared__ double dinv[NN];
    __shared__ double Asm[NN * NN];
    int t = threadIdx.x;
    for (int k = t; k < NN * NN; k += blockDim.x) Asm[k] = 0.0;
    if (t < NN) deg[t] = 1.0;  // self loop weight 1
    __syncthreads();
    if (t == 0) {
        for (int e = 0; e < EDGES; e++) deg[ei[EDGES + e]] += (double)ew[e];
        for (int i = 0; i < NN; i++) dinv[i] = deg[i] > 0.0 ? 1.0 / sqrt(deg[i]) : 0.0;
        for (int e = 0; e < EDGES; e++) {
            int s = ei[e], d = ei[EDGES + e];
            Asm[d * NN + s] += dinv[s] * (double)ew[e] * dinv[d];
        }
        for (int i = 0; i < NN; i++) Asm[i * NN + i] += dinv[i] * dinv[i];
    }
    __syncthreads();
    for (int k = t; k < NN * NN; k += blockDim.x) Aout[k] = (float)Asm[k];
}

// ---- Prologue: repack bottom halves of (256,128) concat weights ----
// out[c][col] = float4 over k=4c..4c+3 of src[(128+k)*128 + f]
__global__ void pack_bot(const float* __restrict__ w0, const float* __restrict__ w1,
                         float4* __restrict__ out, int ngate) {
    int t = blockIdx.x * blockDim.x + threadIdx.x;
    int ncol = ngate * 128;
    int total = 32 * ncol;
    if (t >= total) return;
    int c = t / ncol, col = t - c * ncol;
    const float* src = (col < 128) ? w0 : w1;
    int f = col & 127;
    int k = 4 * c;
    float4 v;
    v.x = src[(128 + k + 0) * 128 + f];
    v.y = src[(128 + k + 1) * 128 + f];
    v.z = src[(128 + k + 2) * 128 + f];
    v.w = src[(128 + k + 3) * 128 + f];
    out[t] = v;
}

// ---- Prologue: Weff2_g = Wg_2 @ lgw_2_top, packed [c][g*128+f], fp64 accum ----
__global__ void make_weff2(const float* __restrict__ Wz2, const float* __restrict__ Wr2,
                           const float* __restrict__ Wh2,
                           const float* __restrict__ lzw2, const float* __restrict__ lrw2,
                           const float* __restrict__ lhw2,
                           float4* __restrict__ out) {
    int t = blockIdx.x * blockDim.x + threadIdx.x;  // [0, 32*384)
    if (t >= 32 * 384) return;
    int c = t / 384, col = t - c * 384;
    int g = col >> 7, f = col & 127;
    const float* W = (g == 0) ? Wz2 : (g == 1) ? Wr2 : Wh2;
    const float* L = (g == 0) ? lzw2 : (g == 1) ? lrw2 : lhw2;
    double a0 = 0, a1 = 0, a2 = 0, a3 = 0;
    for (int m = 0; m < 128; m++) {
        double lm = (double)L[m * 128 + f];
        a0 += (double)W[(4 * c + 0) * 128 + m] * lm;
        a1 += (double)W[(4 * c + 1) * 128 + m] * lm;
        a2 += (double)W[(4 * c + 2) * 128 + m] * lm;
        a3 += (double)W[(4 * c + 3) * 128 + m] * lm;
    }
    out[t] = make_float4((float)a0, (float)a1, (float)a2, (float)a3);
}

// ---- Prologue: layer-1 effective row vectors + all bias consts (fp64) ----
__global__ void make_vecs(const float* __restrict__ Wz1, const float* __restrict__ Wr1,
                          const float* __restrict__ Wh1,
                          const float* __restrict__ bz1, const float* __restrict__ br1,
                          const float* __restrict__ bh1,
                          const float* __restrict__ lzw1, const float* __restrict__ lrw1,
                          const float* __restrict__ lhw1,
                          const float* __restrict__ lzb1, const float* __restrict__ lrb1,
                          const float* __restrict__ lhb1,
                          const float* __restrict__ bz2, const float* __restrict__ br2,
                          const float* __restrict__ bh2,
                          const float* __restrict__ lzw2, const float* __restrict__ lrw2,
                          const float* __restrict__ lhw2,
                          const float* __restrict__ lzb2, const float* __restrict__ lrb2,
                          const float* __restrict__ lhb2,
                          float* __restrict__ out) {
    int t = blockIdx.x * blockDim.x + threadIdx.x;
    if (t >= 9 * 128) return;
    int v = t >> 7, f = t & 127;
    double acc = 0.0;
    if (v < 3) {
        const float* W = (v == 0) ? Wz1 : (v == 1) ? Wr1 : Wh1;   // (1,128)
        const float* L = (v == 0) ? lzw1 : (v == 1) ? lrw1 : lhw1;
        for (int m = 0; m < 128; m++) acc += (double)W[m] * (double)L[m * 128 + f];
    } else if (v < 6) {
        int g = v - 3;
        const float* bb = (g == 0) ? bz1 : (g == 1) ? br1 : bh1;
        const float* L  = (g == 0) ? lzw1 : (g == 1) ? lrw1 : lhw1;
        const float* lb = (g == 0) ? lzb1 : (g == 1) ? lrb1 : lhb1;
        for (int m = 0; m < 128; m++) acc += (double)bb[m] * (double)L[m * 128 + f];
        acc += (double)lb[f];
    } else {
        int g = v - 6;
        const float* bb = (g == 0) ? bz2 : (g == 1) ? br2 : bh2;
        const float* L  = (g == 0) ? lzw2 : (g == 1) ? lrw2 : lhw2;
        const float* lb = (g == 0) ? lzb2 : (g == 1) ? lrb2 : lhb2;
        for (int m = 0; m < 128; m++) acc += (double)bb[m] * (double)L[m * 128 + f];
        acc += (double)lb[f];
    }
    out[t] = (float)acc;
}

// ---- Main: one block per batch element, T=500 steps in-kernel ----
__global__ __launch_bounds__(896) void tgcn_main(
    const float* __restrict__ x,       // (64,500,21)
    const float* __restrict__ ws,
    const float* __restrict__ cls_w,   // (128,1)
    const float* __restrict__ cls_b,   // (1,)
    float* __restrict__ out)           // (64,)
{
    const int b  = blockIdx.x;
    const int t  = threadIdx.x;
    const int f  = t & 127;
    const int ig = t >> 7;            // 0..6
    const int i0 = ig, i1 = ig + 7, i2 = ig + 14;

    __shared__ __align__(16) float sH1[NN * HID];
    __shared__ __align__(16) float sH2[NN * HID];
    __shared__ __align__(16) float sHR[NN * HID];
    __shared__ __align__(16) float sAH[NN * HID];
    __shared__ float sA[NN * NN];
    __shared__ float sax[2][NN];
    __shared__ double sred[7][HID];

    const float*  vecs = ws + WS_VEC;
    const float4* Lzr1 = (const float4*)(ws + WS_LZR1);
    const float4* Lh1  = (const float4*)(ws + WS_LH1);
    const float4* We2  = (const float4*)(ws + WS_WE2);
    const float4* Lzr2 = (const float4*)(ws + WS_LZR2);
    const float4* Lh2  = (const float4*)(ws + WS_LH2);

    const float4* H1v = (const float4*)sH1;   // row stride 32 float4
    const float4* H2v = (const float4*)sH2;
    const float4* HRv = (const float4*)sHR;
    const float4* AHv = (const float4*)sAH;

    for (int k = t; k < NN * HID; k += 896) { sH1[k] = 0.0f; sH2[k] = 0.0f; }
    for (int k = t; k < NN * NN; k += 896) sA[k] = ws[WS_A + k];

    const float wz1e = vecs[f],        wr1e = vecs[128 + f], wh1e = vecs[256 + f];
    const float cz1  = vecs[384 + f],  cr1  = vecs[512 + f], ch1  = vecs[640 + f];
    const float cz2  = vecs[768 + f],  cr2  = vecs[896 + f], ch2  = vecs[1024 + f];

    __syncthreads();

    const float* xb = x + (size_t)b * (TSTEPS * NN);
    if (t < NN) {  // sax for step 0
        float a = 0.0f;
        for (int j = 0; j < NN; j++) a = fmaf(sA[t * NN + j], xb[j], a);
        sax[0][t] = a;
    }
    __syncthreads();

    double oacc = 0.0;

    for (int step = 0; step < TSTEPS; step++) {
        const int pb = step & 1;
        // ---------- P1: layer-1 z,r gates ----------
        const float ax0 = sax[pb][i0], ax1 = sax[pb][i1], ax2 = sax[pb][i2];
        float az0 = fmaf(ax0, wz1e, cz1), az1 = fmaf(ax1, wz1e, cz1), az2 = fmaf(ax2, wz1e, cz1);
        float ar0 = fmaf(ax0, wr1e, cr1), ar1 = fmaf(ax1, wr1e, cr1), ar2 = fmaf(ax2, wr1e, cr1);
        #pragma unroll 4
        for (int c = 0; c < 32; ++c) {
            const float4 wz = Lzr1[c * 256 + f];
            const float4 wr = Lzr1[c * 256 + 128 + f];
            const float4 h0 = H1v[i0 * 32 + c];
            const float4 h1 = H1v[i1 * 32 + c];
            const float4 h2 = H1v[i2 * 32 + c];
            az0 = fma4(h0, wz, az0); az1 = fma4(h1, wz, az1); az2 = fma4(h2, wz, az2);
            ar0 = fma4(h0, wr, ar0); ar1 = fma4(h1, wr, ar1); ar2 = fma4(h2, wr, ar2);
        }
        const float z0 = sigmoidf(az0), z1 = sigmoidf(az1), z2 = sigmoidf(az2);
        const float r0 = sigmoidf(ar0), r1 = sigmoidf(ar1), r2 = sigmoidf(ar2);
        const float h1c0 = sH1[i0 * HID + f], h1c1 = sH1[i1 * HID + f], h1c2 = sH1[i2 * HID + f];
        sHR[i0 * HID + f] = h1c0 * r0;
        sHR[i1 * HID + f] = h1c1 * r1;
        sHR[i2 * HID + f] = h1c2 * r2;
        __syncthreads();

        // ---------- P2: layer-1 h gate + H1 update ----------
        float ah0 = fmaf(ax0, wh1e, ch1), ah1 = fmaf(ax1, wh1e, ch1), ah2 = fmaf(ax2, wh1e, ch1);
        #pragma unroll 4
        for (int c = 0; c < 32; ++c) {
            const float4 wh = Lh1[c * 128 + f];
            const float4 q0 = HRv[i0 * 32 + c];
            const float4 q1 = HRv[i1 * 32 + c];
            const float4 q2 = HRv[i2 * 32 + c];
            ah0 = fma4(q0, wh, ah0); ah1 = fma4(q1, wh, ah1); ah2 = fma4(q2, wh, ah2);
        }
        const float ht0 = tanhf(ah0), ht1 = tanhf(ah1), ht2 = tanhf(ah2);
        const float n0 = fmaf(z0, h1c0, (1.0f - z0) * ht0);
        const float n1 = fmaf(z1, h1c1, (1.0f - z1) * ht1);
        const float n2 = fmaf(z2, h1c2, (1.0f - z2) * ht2);
        sH1[i0 * HID + f] = n0;
        sH1[i1 * HID + f] = n1;
        sH1[i2 * HID + f] = n2;
        __syncthreads();

        // ---------- P3: AH1 = A @ H1 ----------
        float aa0 = 0.0f, aa1 = 0.0f, aa2 = 0.0f;
        #pragma unroll
        for (int j = 0; j < NN; j++) {
            const float hj = sH1[j * HID + f];
            aa0 = fmaf(sA[i0 * NN + j], hj, aa0);
            aa1 = fmaf(sA[i1 * NN + j], hj, aa1);
            aa2 = fmaf(sA[i2 * NN + j], hj, aa2);
        }
        sAH[i0 * HID + f] = aa0;
        sAH[i1 * HID + f] = aa1;
        sAH[i2 * HID + f] = aa2;
        __syncthreads();

        // ---------- P4: layer-2 gcn (all gates) + z,r gates ----------
        float pz0 = cz2, pz1 = cz2, pz2 = cz2;
        float pr0 = cr2, pr1 = cr2, pr2 = cr2;
        float ph0 = ch2, ph1 = ch2, ph2 = ch2;
        #pragma unroll 2
        for (int c = 0; c < 32; ++c) {
            const float4 wz = We2[c * 384 + f];
            const float4 wr = We2[c * 384 + 128 + f];
            const float4 wh = We2[c * 384 + 256 + f];
            const float4 lz = Lzr2[c * 256 + f];
            const float4 lr = Lzr2[c * 256 + 128 + f];
            const float4 a0 = AHv[i0 * 32 + c];
            const float4 a1 = AHv[i1 * 32 + c];
            const float4 a2 = AHv[i2 * 32 + c];
            const float4 g0 = H2v[i0 * 32 + c];
            const float4 g1 = H2v[i1 * 32 + c];
            const float4 g2 = H2v[i2 * 32 + c];
            pz0 = fma4(a0, wz, pz0); pz0 = fma4(g0, lz, pz0);
            pz1 = fma4(a1, wz, pz1); pz1 = fma4(g1, lz, pz1);
            pz2 = fma4(a2, wz, pz2); pz2 = fma4(g2, lz, pz2);
            pr0 = fma4(a0, wr, pr0); pr0 = fma4(g0, lr, pr0);
            pr1 = fma4(a1, wr, pr1); pr1 = fma4(g1, lr, pr1);
            pr2 = fma4(a2, wr, pr2); pr2 = fma4(g2, lr, pr2);
            ph0 = fma4(a0, wh, ph0);
            ph1 = fma4(a1, wh, ph1);
            ph2 = fma4(a2, wh, ph2);
        }
        const float z20 = sigmoidf(pz0), z21 = sigmoidf(pz1), z22 = sigmoidf(pz2);
        const float r20 = sigmoidf(pr0), r21 = sigmoidf(pr1), r22 = sigmoidf(pr2);
        const float h2c0 = sH2[i0 * HID + f], h2c1 = sH2[i1 * HID + f], h2c2 = sH2[i2 * HID + f];
        sHR[i0 * HID + f] = h2c0 * r20;
        sHR[i1 * HID + f] = h2c1 * r21;
        sHR[i2 * HID + f] = h2c2 * r22;
        __syncthreads();

        // ---------- P5: layer-2 h gate + H2 update + output accum ----------
        #pragma unroll 4
        for (int c = 0; c < 32; ++c) {
            const float4 lh = Lh2[c * 128 + f];
            const float4 q0 = HRv[i0 * 32 + c];
            const float4 q1 = HRv[i1 * 32 + c];
            const float4 q2 = HRv[i2 * 32 + c];
            ph0 = fma4(q0, lh, ph0); ph1 = fma4(q1, lh, ph1); ph2 = fma4(q2, lh, ph2);
        }
        const float u0 = tanhf(ph0), u1 = tanhf(ph1), u2 = tanhf(ph2);
        const float m0 = fmaf(z20, h2c0, (1.0f - z20) * u0);
        const float m1 = fmaf(z21, h2c1, (1.0f - z21) * u1);
        const float m2 = fmaf(z22, h2c2, (1.0f - z22) * u2);
        sH2[i0 * HID + f] = m0;
        sH2[i1 * HID + f] = m1;
        sH2[i2 * HID + f] = m2;
        oacc += (double)m0 + (double)m1 + (double)m2;

        // prefetch next step's ax (wave 0 only; covered by the closing barrier)
        if (step + 1 < TSTEPS && t < NN) {
            const float* xt = xb + (step + 1) * NN;
            float a = 0.0f;
            for (int j = 0; j < NN; j++) a = fmaf(sA[t * NN + j], xt[j], a);
            sax[(step + 1) & 1][t] = a;
        }
        __syncthreads();
    }

    // ---------- Epilogue: mean over (T, nodes), dot with cls_w ----------
    sred[ig][f] = oacc;
    __syncthreads();
    if (t < HID) {
        double s = 0.0;
        for (int g = 0; g < 7; g++) s += sred[g][f];
        sred[0][f] = (s / (double)(TSTEPS * NN)) * (double)cls_w[f];
    }
    __syncthreads();
    if (t < 64) {
        double v = ((double*)sred)[t] + ((double*)sred)[t + 64];
        for (int off = 32; off; off >>= 1) v += __shfl_down(v, off, 64);
        if (t == 0) out[b] = (float)(v + (double)cls_b[0]);
    }
}

extern "C" void kernel_launch(void* const* d_in, const int* in_sizes, int n_in,
                              void* d_out, int out_size, void* d_ws, size_t ws_size,
                              hipStream_t stream) {
    const float* x    = (const float*)d_in[0];
    const int*   ei   = (const int*)  d_in[1];
    const float* ew   = (const float*)d_in[2];
    const float* Wz1  = (const float*)d_in[3];
    const float* bz1  = (const float*)d_in[4];
    const float* lzw1 = (const float*)d_in[5];
    const float* lzb1 = (const float*)d_in[6];
    const float* Wr1  = (const float*)d_in[7];
    const float* br1  = (const float*)d_in[8];
    const float* lrw1 = (const float*)d_in[9];
    const float* lrb1 = (const float*)d_in[10];
    const float* Wh1  = (const float*)d_in[11];
    const float* bh1  = (const float*)d_in[12];
    const float* lhw1 = (const float*)d_in[13];
    const float* lhb1 = (const float*)d_in[14];
    const float* Wz2  = (const float*)d_in[15];
    const float* bz2  = (const float*)d_in[16];
    const float* lzw2 = (const float*)d_in[17];
    const float* lzb2 = (const float*)d_in[18];
    const float* Wr2  = (const float*)d_in[19];
    const float* br2  = (const float*)d_in[20];
    const float* lrw2 = (const float*)d_in[21];
    const float* lrb2 = (const float*)d_in[22];
    const float* Wh2  = (const float*)d_in[23];
    const float* bh2  = (const float*)d_in[24];
    const float* lhw2 = (const float*)d_in[25];
    const float* lhb2 = (const float*)d_in[26];
    const float* clsw = (const float*)d_in[27];
    const float* clsb = (const float*)d_in[28];

    float* ws   = (float*)d_ws;
    float* outp = (float*)d_out;

    build_A<<<1, 64, 0, stream>>>(ei, ew, ws + WS_A);
    pack_bot<<<32, 256, 0, stream>>>(lzw1, lrw1, (float4*)(ws + WS_LZR1), 2);
    pack_bot<<<16, 256, 0, stream>>>(lhw1, lhw1, (float4*)(ws + WS_LH1), 1);
    pack_bot<<<32, 256, 0, stream>>>(lzw2, lrw2, (float4*)(ws + WS_LZR2), 2);
    pack_bot<<<16, 256, 0, stream>>>(lhw2, lhw2, (float4*)(ws + WS_LH2), 1);
    make_weff2<<<48, 256, 0, stream>>>(Wz2, Wr2, Wh2, lzw2, lrw2, lhw2,
                                       (float4*)(ws + WS_WE2));
    make_vecs<<<5, 256, 0, stream>>>(Wz1, Wr1, Wh1, bz1, br1, bh1,
                                     lzw1, lrw1, lhw1, lzb1, lrb1, lhb1,
                                     bz2, br2, bh2, lzw2, lrw2, lhw2,
                                     lzb2, lrb2, lhb2, ws + WS_VEC);
    tgcn_main<<<64, 896, 0, stream>>>(x, ws, clsw, clsb, outp);
}